// Round 1
// baseline (12.656 us; speedup 1.0000x reference)
//
#include <hip/hip_runtime.h>

#define NB 4
#define NN 1024
#define DK 64      // Din
#define DO 64      // Dout
#define CHUNKS 64  // n-chunks per batch
#define RPC 16     // rows per chunk
#define WPAD 68    // Wt row stride (floats): 16B-aligned rows, breaks transposed-write conflicts
#define XPAD 68

// K1: for block (b, ch): rows m = ch*16 .. ch*16+15
//   out[b,m,o]        = sum_d x[b,m,d] * W[o*128 + 64 + d]          (c-dot)
//   ws[(b*64+ch)*64+o] = max_rows sum_d x[b,m,d] * W[o*128 + d]      (a-dot partial max)
__global__ __launch_bounds__(256) void pe_k1(const float* __restrict__ x,
                                             const float* __restrict__ W,
                                             float* __restrict__ out,
                                             float* __restrict__ wsmax) {
    __shared__ float Wt[128 * WPAD];   // Wt[k*WPAD + o] = W[o*128 + k]
    __shared__ float xs[RPC * XPAD];
    __shared__ float red[16 * 64];

    const int t  = threadIdx.x;
    const int bi = blockIdx.x;
    const int b  = bi >> 6;          // / CHUNKS
    const int ch = bi & 63;
    const int m0 = ch * RPC;

    // ---- stage W transposed (8192 floats) ----
    const float4* W4 = (const float4*)W;
    #pragma unroll
    for (int i = 0; i < 8; ++i) {
        int g4 = t + 256 * i;            // 0..2047
        float4 wv = W4[g4];
        int base = g4 * 4;
        int o = base >> 7;               // 0..63
        int k = base & 127;              // multiple of 4
        Wt[(k + 0) * WPAD + o] = wv.x;
        Wt[(k + 1) * WPAD + o] = wv.y;
        Wt[(k + 2) * WPAD + o] = wv.z;
        Wt[(k + 3) * WPAD + o] = wv.w;
    }
    // ---- stage x rows (16 x 64 floats) ----
    {
        const float4* x4 = (const float4*)(x + ((size_t)b * NN + m0) * DK);
        float4 xv = x4[t];               // 256 float4 = 1024 floats
        int base = t * 4;
        int r = base >> 6;
        int d = base & 63;
        *(float4*)&xs[r * XPAD + d] = xv;
    }
    __syncthreads();

    const int og = t & 15;   // o-quad index: o = og*4 .. og*4+3
    const int r  = t >> 4;   // row 0..15

    float4 aa = make_float4(0.f, 0.f, 0.f, 0.f);
    float4 cc = make_float4(0.f, 0.f, 0.f, 0.f);
    const float* xr = &xs[r * XPAD];

    #pragma unroll
    for (int d = 0; d < 64; d += 4) {
        float4 xq = *(const float4*)&xr[d];
        float xv[4] = {xq.x, xq.y, xq.z, xq.w};
        #pragma unroll
        for (int j = 0; j < 4; ++j) {
            float xs_ = xv[j];
            float4 w1 = *(const float4*)&Wt[(d + j) * WPAD + og * 4];
            float4 w2 = *(const float4*)&Wt[(64 + d + j) * WPAD + og * 4];
            aa.x += xs_ * w1.x; aa.y += xs_ * w1.y; aa.z += xs_ * w1.z; aa.w += xs_ * w1.w;
            cc.x += xs_ * w2.x; cc.y += xs_ * w2.y; cc.z += xs_ * w2.z; cc.w += xs_ * w2.w;
        }
    }

    // c-dot -> out (coalesced float4)
    {
        size_t oidx = (((size_t)b * NN) + (m0 + r)) * DO + og * 4;
        *(float4*)&out[oidx] = cc;
    }

    // a-dot partial max over rows of this chunk -> ws
    *(float4*)&red[r * 64 + og * 4] = aa;
    __syncthreads();
    if (t < 64) {
        float v = red[t];
        #pragma unroll
        for (int rr = 1; rr < 16; ++rr) v = fmaxf(v, red[rr * 64 + t]);
        wsmax[((size_t)b * CHUNKS + ch) * 64 + t] = v;
    }
}

// K2: out[b,m,o] += max_ch ws[b][ch][o] + bias[o]
__global__ __launch_bounds__(256) void pe_k2(const float* __restrict__ bias,
                                             const float* __restrict__ wsmax,
                                             float* __restrict__ out) {
    __shared__ float addv[64];
    const int t  = threadIdx.x;
    const int bi = blockIdx.x;
    const int b  = bi >> 6;
    const int rb = bi & 63;              // 16-row block within batch

    if (t < 64) {
        const float* wp = wsmax + (size_t)b * CHUNKS * 64 + t;
        float v = wp[0];
        #pragma unroll
        for (int ch = 1; ch < CHUNKS; ++ch) v = fmaxf(v, wp[ch * 64]);
        addv[t] = v + bias[t];
    }
    __syncthreads();

    size_t base = ((size_t)b * NN + rb * 16) * DO;
    float4* o4 = (float4*)(out + base);
    float4 val = o4[t];                  // 256 float4 = 16 rows x 64 cols
    int oc = (t & 15) * 4;
    val.x += addv[oc + 0];
    val.y += addv[oc + 1];
    val.z += addv[oc + 2];
    val.w += addv[oc + 3];
    o4[t] = val;
}

extern "C" void kernel_launch(void* const* d_in, const int* in_sizes, int n_in,
                              void* d_out, int out_size, void* d_ws, size_t ws_size,
                              hipStream_t stream) {
    const float* x    = (const float*)d_in[0];
    const float* W    = (const float*)d_in[1];
    const float* bias = (const float*)d_in[2];
    float* out   = (float*)d_out;
    float* wsmax = (float*)d_ws;   // needs 4*64*64*4 = 64 KiB

    pe_k1<<<NB * CHUNKS, 256, 0, stream>>>(x, W, out, wsmax);
    pe_k2<<<NB * 64, 256, 0, stream>>>(bias, wsmax, out);
}

// Round 2
// 12.654 us; speedup vs baseline: 1.0002x; 1.0002x over previous
//
#include <hip/hip_runtime.h>

#define WPAD 68   // padded row stride (floats); 68*4=272 B keeps float4 rows 16B-aligned

// ---------------------------------------------------------------------------
// K1: per (b, 16-row chunk) compute a[b,n,o] = x[b,n,:]·W1[o,:] and reduce
//     max over the chunk's 16 rows -> wsmax[b][ch][o]  (16 KB total)
// ---------------------------------------------------------------------------
__global__ __launch_bounds__(256) void pe_k1(const float* __restrict__ x,
                                             const float* __restrict__ W,
                                             float* __restrict__ wsmax) {
    __shared__ float Wt[64 * WPAD];   // Wt[k*WPAD+o] = W1[o][k]
    __shared__ float xs[16 * WPAD];
    __shared__ float red[16 * 64];

    const int t  = threadIdx.x;
    const int b  = blockIdx.x >> 6;
    const int ch = blockIdx.x & 63;
    const int m0 = ch << 4;

    // stage W1^T (16 KB). id -> o=id>>4 (row), q=id&15 (k-quad)
    const float4* W4 = (const float4*)W;   // W row = 128 floats = 32 float4
    #pragma unroll
    for (int i = 0; i < 4; ++i) {
        int id = t + 256 * i;
        int o = id >> 4, q = id & 15;
        float4 wv = W4[o * 32 + q];        // W1 half: k = 4q..4q+3
        Wt[(4 * q + 0) * WPAD + o] = wv.x;
        Wt[(4 * q + 1) * WPAD + o] = wv.y;
        Wt[(4 * q + 2) * WPAD + o] = wv.z;
        Wt[(4 * q + 3) * WPAD + o] = wv.w;
    }
    // stage x rows (4 KB)
    {
        const float4* x4 = (const float4*)(x + ((size_t)b * 1024 + m0) * 64);
        float4 xv = x4[t];
        *(float4*)&xs[(t >> 4) * WPAD + 4 * (t & 15)] = xv;
    }
    __syncthreads();

    const int r  = t >> 4;
    const int og = t & 15;
    const float* xr = &xs[r * WPAD];
    float ax = 0.f, ay = 0.f, az = 0.f, aw = 0.f;

    #pragma unroll
    for (int q = 0; q < 16; ++q) {
        float4 xq = *(const float4*)&xr[4 * q];
        float4 w0 = *(const float4*)&Wt[(4 * q + 0) * WPAD + og * 4];
        float4 w1 = *(const float4*)&Wt[(4 * q + 1) * WPAD + og * 4];
        float4 w2 = *(const float4*)&Wt[(4 * q + 2) * WPAD + og * 4];
        float4 w3 = *(const float4*)&Wt[(4 * q + 3) * WPAD + og * 4];
        ax += xq.x * w0.x; ay += xq.x * w0.y; az += xq.x * w0.z; aw += xq.x * w0.w;
        ax += xq.y * w1.x; ay += xq.y * w1.y; az += xq.y * w1.z; aw += xq.y * w1.w;
        ax += xq.z * w2.x; ay += xq.z * w2.y; az += xq.z * w2.z; aw += xq.z * w2.w;
        ax += xq.w * w3.x; ay += xq.w * w3.y; az += xq.w * w3.z; aw += xq.w * w3.w;
    }
    *(float4*)&red[r * 64 + og * 4] = make_float4(ax, ay, az, aw);
    __syncthreads();

    if (t < 64) {
        float v = red[t];
        #pragma unroll
        for (int rr = 1; rr < 16; ++rr) v = fmaxf(v, red[rr * 64 + t]);
        wsmax[((size_t)(b << 6) + ch) * 64 + t] = v;
    }
}

// ---------------------------------------------------------------------------
// K2: per (b, 16-row chunk):
//   amax[o] = max_ch wsmax[b][ch][o];  out[b,m,o] = x[b,m,:]·W2[o,:] + amax[o] + bias[o]
//   out written exactly once, coalesced float4.
// ---------------------------------------------------------------------------
__global__ __launch_bounds__(256) void pe_k2(const float* __restrict__ x,
                                             const float* __restrict__ W,
                                             const float* __restrict__ bias,
                                             const float* __restrict__ wsmax,
                                             float* __restrict__ out) {
    __shared__ float Wt[64 * WPAD];   // Wt[k*WPAD+o] = W2[o][k]
    __shared__ float xs[16 * WPAD];
    __shared__ float amx[4 * 64];
    __shared__ float addv[64];

    const int t  = threadIdx.x;
    const int b  = blockIdx.x >> 6;
    const int ch = blockIdx.x & 63;
    const int m0 = ch << 4;

    // stage W2^T
    const float4* W4 = (const float4*)W;
    #pragma unroll
    for (int i = 0; i < 4; ++i) {
        int id = t + 256 * i;
        int o = id >> 4, q = id & 15;
        float4 wv = W4[o * 32 + 16 + q];   // W2 half: k = 64 + 4q ..
        Wt[(4 * q + 0) * WPAD + o] = wv.x;
        Wt[(4 * q + 1) * WPAD + o] = wv.y;
        Wt[(4 * q + 2) * WPAD + o] = wv.z;
        Wt[(4 * q + 3) * WPAD + o] = wv.w;
    }
    // stage x rows
    {
        const float4* x4 = (const float4*)(x + ((size_t)b * 1024 + m0) * 64);
        float4 xv = x4[t];
        *(float4*)&xs[(t >> 4) * WPAD + 4 * (t & 15)] = xv;
    }
    // partial amax: thread t handles o = t&63 over chunks {g, g+4, ..., g+60}
    {
        const int o = t & 63, g = t >> 6;
        const float* wp = wsmax + (size_t)b * 4096 + o;
        float v = wp[(size_t)g * 64];
        #pragma unroll
        for (int s = 1; s < 16; ++s) v = fmaxf(v, wp[(size_t)(g + 4 * s) * 64]);
        amx[g * 64 + o] = v;
    }
    __syncthreads();
    if (t < 64) {
        float v = fmaxf(fmaxf(amx[t], amx[64 + t]), fmaxf(amx[128 + t], amx[192 + t]));
        addv[t] = v + bias[t];
    }
    __syncthreads();

    const int r  = t >> 4;
    const int og = t & 15;
    const float* xr = &xs[r * WPAD];
    float4 add = *(const float4*)&addv[og * 4];
    float cx = add.x, cy = add.y, cz = add.z, cw = add.w;

    #pragma unroll
    for (int q = 0; q < 16; ++q) {
        float4 xq = *(const float4*)&xr[4 * q];
        float4 w0 = *(const float4*)&Wt[(4 * q + 0) * WPAD + og * 4];
        float4 w1 = *(const float4*)&Wt[(4 * q + 1) * WPAD + og * 4];
        float4 w2 = *(const float4*)&Wt[(4 * q + 2) * WPAD + og * 4];
        float4 w3 = *(const float4*)&Wt[(4 * q + 3) * WPAD + og * 4];
        cx += xq.x * w0.x; cy += xq.x * w0.y; cz += xq.x * w0.z; cw += xq.x * w0.w;
        cx += xq.y * w1.x; cy += xq.y * w1.y; cz += xq.y * w1.z; cw += xq.y * w1.w;
        cx += xq.z * w2.x; cy += xq.z * w2.y; cz += xq.z * w2.z; cw += xq.z * w2.w;
        cx += xq.w * w3.x; cy += xq.w * w3.y; cz += xq.w * w3.z; cw += xq.w * w3.w;
    }

    size_t oidx = ((size_t)b * 1024 + (m0 + r)) * 64 + og * 4;
    *(float4*)&out[oidx] = make_float4(cx, cy, cz, cw);
}

extern "C" void kernel_launch(void* const* d_in, const int* in_sizes, int n_in,
                              void* d_out, int out_size, void* d_ws, size_t ws_size,
                              hipStream_t stream) {
    const float* x    = (const float*)d_in[0];
    const float* W    = (const float*)d_in[1];
    const float* bias = (const float*)d_in[2];
    float* out   = (float*)d_out;
    float* wsmax = (float*)d_ws;   // 4*64*64*4 = 64 KiB used

    pe_k1<<<4 * 64, 256, 0, stream>>>(x, W, wsmax);
    pe_k2<<<4 * 64, 256, 0, stream>>>(x, W, bias, wsmax, out);
}